// Round 8
// baseline (274.214 us; speedup 1.0000x reference)
//
#include <hip/hip_runtime.h>

// Problem constants
#define B_  2
#define L_  128
#define D_  256
#define H_  8
#define R_  4
#define BL_ (B_*L_)
#define SXP 260    // padded row stride (floats) for LDS row arrays
#define NBLK 512   // 2 blocks/CU on 256 CUs — co-residency by capacity

// NOTE (R7 lesson): hipLaunchCooperativeKernel does NOT work in this harness
// (kernel never executes, output stays at memset value). Grid-wide sync is
// done with a device-scope atomic barrier instead; counter lives in d_ws and
// is zeroed by a captured hipMemsetAsync before each launch.

__device__ __forceinline__ float wredsum64(float v) {
    #pragma unroll
    for (int m = 32; m >= 1; m >>= 1) v += __shfl_xor(v, m, 64);
    return v;
}
__device__ __forceinline__ float wredmax64(float v) {
    #pragma unroll
    for (int m = 32; m >= 1; m >>= 1) v = fmaxf(v, __shfl_xor(v, m, 64));
    return v;
}

// Monotonic grid barrier: phase p waits until counter reaches p*NBLK.
__device__ __forceinline__ void grid_barrier(unsigned* bar, unsigned target) {
    __threadfence();                                   // release my block's stores (agent scope)
    __syncthreads();
    if (threadIdx.x == 0) {
        __hip_atomic_fetch_add(bar, 1u, __ATOMIC_ACQ_REL, __HIP_MEMORY_SCOPE_AGENT);
        while (__hip_atomic_load(bar, __ATOMIC_ACQUIRE, __HIP_MEMORY_SCOPE_AGENT) < target)
            __builtin_amdgcn_s_sleep(2);
    }
    __syncthreads();
    __threadfence();                                   // acquire: drop stale lines
}

// One persistent kernel, grid 512 x 256, two software grid barriers.
// Stage A (proj): 64 rowTiles(4 rows) x 8 cg(32 cols = 1 head).
// Stage B (attn): b x 32 iTiles(4 i, one per wave) x 8 heads.
// Stage C (fc):   64 rowTiles(4 rows) x 8 cg(32 cols).
__global__ __launch_bounds__(256, 2) void k_fused(
    const float* __restrict__ q, const float* __restrict__ k, const float* __restrict__ v,
    const float* __restrict__ t, const float* __restrict__ omega,
    const float* __restrict__ Wq, const float* __restrict__ Wk, const float* __restrict__ Wv,
    const float* __restrict__ s, const float* __restrict__ fc_w, const float* __restrict__ fc_b,
    const float* __restrict__ ln_g, const float* __restrict__ ln_b,
    float* __restrict__ pv, float* __restrict__ qkdot, float* __restrict__ mid,
    unsigned* __restrict__ bar, float* __restrict__ dout)
{
    const int blk = blockIdx.x;
    const int tid = threadIdx.x;

    __shared__ __align__(16) union {
        struct {                          // stage A: ~17.6 KB
            float sx[3][4 * SXP];
            float partF[8 * 4 * 32];      // [kg][row][col32]
            float spq[4][32], spk[4][32];
        } a;
        struct {                          // stage B: ~29.7 KB
            float sQK[L_ * H_];           // [j][h]
            float sQKh[L_];
            float sOm[4 * L_];
            float sPhi[4 * L_], sPsi[4 * L_];
            float sAttn[4 * L_];
            float partF[32 * 4 * 32];     // [jg][w][col32]
            float st[L_];
            float sS[R_];
        } b;
        struct {                          // stage C: ~8.3 KB
            float smid[4 * SXP];
            float partF[8 * 4 * 32];
        } c;
    } u;

    // ---------------- Stage A: projections ----------------
    {
        const int rowTile = blk >> 3;
        const int cgp = blk & 7;          // 32 cols == head cgp
        const int rbase = rowTile * 4;

        {   // stage q,k,v rows (float4)
            const int r = tid >> 6, f4c = tid & 63;
            #pragma unroll
            for (int p = 0; p < 3; ++p) {
                const float* src = (p == 0 ? q : (p == 1 ? k : v)) + (size_t)(rbase + r) * D_;
                *reinterpret_cast<float4*>(&u.a.sx[p][r * SXP + f4c * 4]) =
                    reinterpret_cast<const float4*>(src)[f4c];
            }
        }
        __syncthreads();

        {   // LayerNorm: wave r owns row r
            const int r = tid >> 6, lane = tid & 63;
            float x0 = u.a.sx[0][r * SXP + lane];
            float x1 = u.a.sx[0][r * SXP + lane + 64];
            float x2 = u.a.sx[0][r * SXP + lane + 128];
            float x3 = u.a.sx[0][r * SXP + lane + 192];
            float s1 = x0 + x1 + x2 + x3;
            float s2 = x0*x0 + x1*x1 + x2*x2 + x3*x3;
            #pragma unroll
            for (int m = 32; m >= 1; m >>= 1) {
                s1 += __shfl_xor(s1, m, 64);
                s2 += __shfl_xor(s2, m, 64);
            }
            const float mu = s1 * (1.0f / D_);
            const float rs = rsqrtf(s2 * (1.0f / D_) - mu * mu + 1e-6f);
            u.a.sx[0][r * SXP + lane      ] = (x0 - mu) * rs * ln_g[lane      ] + ln_b[lane      ];
            u.a.sx[0][r * SXP + lane +  64] = (x1 - mu) * rs * ln_g[lane +  64] + ln_b[lane +  64];
            u.a.sx[0][r * SXP + lane + 128] = (x2 - mu) * rs * ln_g[lane + 128] + ln_b[lane + 128];
            u.a.sx[0][r * SXP + lane + 192] = (x3 - mu) * rs * ln_g[lane + 192] + ln_b[lane + 192];
        }
        __syncthreads();

        // GEMV: thread = (kg 0..7, row 0..3, c4 0..7); 32 K-steps; 4 row-threads
        // share every weight float4 line.
        const int kg  = tid >> 5;
        const int row = (tid >> 3) & 3;
        const int c4  = tid & 7;
        const int gc4 = cgp * 8 + c4;     // global float4 col (0..63)
        const int kbase = kg * 32;

        #pragma unroll
        for (int m = 0; m < 3; ++m) {
            const float4* W4 = reinterpret_cast<const float4*>(m == 0 ? Wq : (m == 1 ? Wk : Wv));
            float4 a = {0, 0, 0, 0};
            #pragma unroll 8
            for (int kk = 0; kk < 32; ++kk) {
                const int kr = kbase + kk;
                const float x = u.a.sx[m][row * SXP + kr];
                const float4 w = W4[kr * 64 + gc4];
                a.x += x * w.x; a.y += x * w.y; a.z += x * w.z; a.w += x * w.w;
            }
            *reinterpret_cast<float4*>(&u.a.partF[kg * 128 + row * 32 + c4 * 4]) = a;
            __syncthreads();
            if (tid < 128) {              // reduce over kg
                const int rr = tid >> 5, cc = tid & 31;
                float sum = 0.f;
                #pragma unroll
                for (int g = 0; g < 8; ++g) sum += u.a.partF[g * 128 + rr * 32 + cc];
                if      (m == 0) u.a.spq[rr][cc] = sum;
                else if (m == 1) u.a.spk[rr][cc] = sum;
                else             pv[(size_t)(rbase + rr) * D_ + cgp * 32 + cc] = sum;
            }
            __syncthreads();
        }

        if (tid < 128) {   // qkdot for head cgp (32-col groups align with heads)
            const int rr = tid >> 5, cc = tid & 31;
            float d = u.a.spq[rr][cc] * u.a.spk[rr][cc];
            #pragma unroll
            for (int m = 16; m >= 1; m >>= 1) d += __shfl_xor(d, m, 64);
            if (cc == 0) qkdot[(size_t)(rbase + rr) * H_ + cgp] = d;
        }
    }

    grid_barrier(bar, NBLK);

    // ---------------- Stage B: attention ----------------
    {
        const int b     = blk >> 8;
        const int itile = (blk >> 3) & 31;     // 4 i per block, one per wave
        const int h     = blk & 7;
        const int ibase = itile * 4;

        {   // staging
            reinterpret_cast<float4*>(u.b.sQK)[tid] =
                reinterpret_cast<const float4*>(qkdot + (size_t)b * L_ * H_)[tid];
            if (tid < 128)
                reinterpret_cast<float4*>(u.b.sOm)[tid] =
                    reinterpret_cast<const float4*>(omega + ((size_t)(b * L_ + ibase)) * L_)[tid];
            if (tid < 32)
                reinterpret_cast<float4*>(u.b.st)[tid] =
                    reinterpret_cast<const float4*>(t + (size_t)b * L_)[tid];
            if (tid < R_) u.b.sS[tid] = s[tid];
        }
        __syncthreads();

        if (tid < 128) u.b.sQKh[tid] = u.b.sQK[tid * H_ + h];
        #pragma unroll
        for (int p = 0; p < 2; ++p) {          // Phi/Psi for 4 i's x 128 j's
            const int idx = tid + p * 256;
            const int w = idx >> 7, j = idx & 127;
            const float dtv = fabsf(u.b.st[ibase + w] - u.b.st[j]);
            float Phi = 0.f, Psi = 0.f;
            #pragma unroll
            for (int r = 0; r < R_; ++r) {
                const float e = expf(-dtv * u.b.sS[r]);
                Phi += e;
                Psi += e * e;
            }
            u.b.sPhi[idx] = Phi;
            u.b.sPsi[idx] = Psi;
        }
        __syncthreads();

        // softmax: wave w -> i = ibase + w
        const int w = tid >> 6, lane = tid & 63;
        {
            const int i = ibase + w;
            const float invtemp = 0.17677669529663687f;  // 1/sqrt(32)
            const int j0 = lane, j1 = lane + 64;
            float l0 = (j0 <= i) ? u.b.sOm[w*L_ + j0] * u.b.sPsi[w*L_ + j0] * u.b.sQKh[j0] * invtemp : -3.0e38f;
            float l1 = (j1 <= i) ? u.b.sOm[w*L_ + j1] * u.b.sPsi[w*L_ + j1] * u.b.sQKh[j1] * invtemp : -3.0e38f;
            const float mx = wredmax64(fmaxf(l0, l1));
            const float e0 = (j0 <= i) ? expf(l0 - mx) : 0.f;
            const float e1 = (j1 <= i) ? expf(l1 - mx) : 0.f;
            const float inv = 1.0f / wredsum64(e0 + e1);
            const float a0 = e0 * inv, a1 = e1 * inv;
            u.b.sAttn[w*L_ + j0] = a0;
            u.b.sAttn[w*L_ + j1] = a1;
            const size_t ab = (size_t)BL_ * D_ + (((size_t)(b * H_ + h) * L_ + i) * L_);
            dout[ab + j0] = a0;
            dout[ab + j1] = a1;
        }
        __syncthreads();

        {   // mid for 4 i's: each pv float4 feeds 4 accumulators
            const int jg = tid >> 3, c4 = tid & 7;
            const int gc4 = h * 8 + c4;
            const float4* pv4 = reinterpret_cast<const float4*>(pv + (size_t)b * L_ * D_);
            float4 acc[4];
            #pragma unroll
            for (int ww = 0; ww < 4; ++ww) acc[ww] = make_float4(0, 0, 0, 0);
            #pragma unroll
            for (int jj = 0; jj < 4; ++jj) {
                const int j = jg + jj * 32;
                const float4 p = pv4[j * 64 + gc4];
                #pragma unroll
                for (int ww = 0; ww < 4; ++ww) {
                    const float wgt = u.b.sAttn[ww*L_ + j] * u.b.sPhi[ww*L_ + j]; // 0 beyond causal
                    acc[ww].x += wgt * p.x; acc[ww].y += wgt * p.y;
                    acc[ww].z += wgt * p.z; acc[ww].w += wgt * p.w;
                }
            }
            #pragma unroll
            for (int ww = 0; ww < 4; ++ww)
                *reinterpret_cast<float4*>(&u.b.partF[jg * 128 + ww * 32 + c4 * 4]) = acc[ww];
        }
        __syncthreads();
        if (tid < 128) {   // reduce over jg
            const int ww = tid >> 5, cc = tid & 31;
            float sum = 0.f;
            #pragma unroll
            for (int g = 0; g < 32; ++g) sum += u.b.partF[g * 128 + ww * 32 + cc];
            mid[((size_t)(b * L_ + ibase + ww)) * D_ + h * 32 + cc] = sum;
        }
    }

    grid_barrier(bar, 2 * NBLK);

    // ---------------- Stage C: fc + bias + residual ----------------
    {
        const int rowTile = blk >> 3;
        const int cgp = blk & 7;
        const int rbase = rowTile * 4;

        {
            const int r = tid >> 6, f4c = tid & 63;
            *reinterpret_cast<float4*>(&u.c.smid[r * SXP + f4c * 4]) =
                reinterpret_cast<const float4*>(mid + (size_t)(rbase + r) * D_)[f4c];
        }
        __syncthreads();

        const int kg  = tid >> 5;
        const int row = (tid >> 3) & 3;
        const int c4  = tid & 7;
        const int gc4 = cgp * 8 + c4;
        const int kbase = kg * 32;
        const float4* fw4 = reinterpret_cast<const float4*>(fc_w);
        float4 a = {0, 0, 0, 0};
        #pragma unroll 8
        for (int kk = 0; kk < 32; ++kk) {
            const int kr = kbase + kk;
            const float x = u.c.smid[row * SXP + kr];
            const float4 wv = fw4[kr * 64 + gc4];
            a.x += x * wv.x; a.y += x * wv.y; a.z += x * wv.z; a.w += x * wv.w;
        }
        *reinterpret_cast<float4*>(&u.c.partF[kg * 128 + row * 32 + c4 * 4]) = a;
        __syncthreads();

        if (tid < 128) {
            const int rr = tid >> 5, cc = tid & 31;
            const int col = cgp * 32 + cc;
            float sum = fc_b[col] + q[(size_t)(rbase + rr) * D_ + col];
            #pragma unroll
            for (int g = 0; g < 8; ++g) sum += u.c.partF[g * 128 + rr * 32 + cc];
            dout[(size_t)(rbase + rr) * D_ + col] = sum;
        }
    }
}

extern "C" void kernel_launch(void* const* d_in, const int* in_sizes, int n_in,
                              void* d_out, int out_size, void* d_ws, size_t ws_size,
                              hipStream_t stream) {
    const float* q     = (const float*)d_in[0];
    const float* k     = (const float*)d_in[1];
    const float* v     = (const float*)d_in[2];
    const float* t     = (const float*)d_in[3];
    const float* omega = (const float*)d_in[4];
    // d_in[5] = mask (bool) — causal triu(1), hardcoded as j<=i, not read
    const float* Wq    = (const float*)d_in[6];
    const float* Wk    = (const float*)d_in[7];
    const float* Wv    = (const float*)d_in[8];
    const float* s     = (const float*)d_in[9];
    const float* fc_w  = (const float*)d_in[10];
    const float* fc_b  = (const float*)d_in[11];
    const float* ln_g  = (const float*)d_in[12];
    const float* ln_b  = (const float*)d_in[13];

    float* ws       = (float*)d_ws;
    float* pv       = ws;                 // BL*D = 65536 floats
    float* qkdot    = ws + 65536;         // BL*H = 2048 floats
    float* mid      = ws + 69632;         // BL*D = 65536 floats
    unsigned* bar   = (unsigned*)(ws + 139264);  // barrier counter (16B-aligned)
    float* out      = (float*)d_out;      // [0,65536): out; [65536,327680): attn

    hipMemsetAsync(bar, 0, sizeof(unsigned), stream);   // zero the barrier counter
    hipLaunchKernelGGL(k_fused, dim3(NBLK), dim3(256), 0, stream,
                       q, k, v, t, omega, Wq, Wk, Wv, s, fc_w, fc_b, ln_g, ln_b,
                       pv, qkdot, mid, bar, out);
}

// Round 9
// 103.473 us; speedup vs baseline: 2.6501x; 2.6501x over previous
//
#include <hip/hip_runtime.h>

// Problem constants
#define B_  2
#define L_  128
#define D_  256
#define H_  8
#define R_  4
#define BL_ (B_*L_)
#define SXP 260   // padded row stride (floats) for LDS row arrays

// R7/R8 lessons: hipLaunchCooperativeKernel never executes in this harness;
// software grid barriers cost ~75us each (atomic contention across 8 XCDs).
// => exactly 2 kernels: proj (cross-row dep boundary), then attn+fc fused.

__device__ __forceinline__ float wredsum64(float v) {
    #pragma unroll
    for (int m = 32; m >= 1; m >>= 1) v += __shfl_xor(v, m, 64);
    return v;
}
__device__ __forceinline__ float wredmax64(float v) {
    #pragma unroll
    for (int m = 32; m >= 1; m >>= 1) v = fmaxf(v, __shfl_xor(v, m, 64));
    return v;
}

// K1 (R6-proven): grid 1024 = 64 rowTiles(4 rows) x 16 cg(16 cols). LN + 3 GEMVs,
// weight lines shared across 4 rows; qk half-head partials -> qkpart; pv -> ws.
__global__ __launch_bounds__(256) void k_proj(
    const float* __restrict__ q, const float* __restrict__ k, const float* __restrict__ v,
    const float* __restrict__ Wq, const float* __restrict__ Wk, const float* __restrict__ Wv,
    const float* __restrict__ ln_g, const float* __restrict__ ln_b,
    float* __restrict__ pv, float* __restrict__ qkpart)
{
    const int blk = blockIdx.x;
    const int rowTile = blk >> 4;
    const int cg = blk & 15;
    const int rbase = rowTile * 4;
    const int tid = threadIdx.x;

    __shared__ __align__(16) float sx[3][4 * SXP];
    __shared__ __align__(16) float partF[16 * 4 * 16];
    __shared__ float spq[4][16], spk[4][16];

    {
        const int r = tid >> 6, f4c = tid & 63;
        #pragma unroll
        for (int p = 0; p < 3; ++p) {
            const float* src = (p == 0 ? q : (p == 1 ? k : v)) + (size_t)(rbase + r) * D_;
            *reinterpret_cast<float4*>(&sx[p][r * SXP + f4c * 4]) =
                reinterpret_cast<const float4*>(src)[f4c];
        }
    }
    __syncthreads();

    {   // LayerNorm: wave r owns row r
        const int r = tid >> 6, lane = tid & 63;
        float x0 = sx[0][r * SXP + lane];
        float x1 = sx[0][r * SXP + lane + 64];
        float x2 = sx[0][r * SXP + lane + 128];
        float x3 = sx[0][r * SXP + lane + 192];
        float s1 = x0 + x1 + x2 + x3;
        float s2 = x0*x0 + x1*x1 + x2*x2 + x3*x3;
        #pragma unroll
        for (int m = 32; m >= 1; m >>= 1) {
            s1 += __shfl_xor(s1, m, 64);
            s2 += __shfl_xor(s2, m, 64);
        }
        const float mu = s1 * (1.0f / D_);
        const float rs = rsqrtf(s2 * (1.0f / D_) - mu * mu + 1e-6f);
        sx[0][r * SXP + lane      ] = (x0 - mu) * rs * ln_g[lane      ] + ln_b[lane      ];
        sx[0][r * SXP + lane +  64] = (x1 - mu) * rs * ln_g[lane +  64] + ln_b[lane +  64];
        sx[0][r * SXP + lane + 128] = (x2 - mu) * rs * ln_g[lane + 128] + ln_b[lane + 128];
        sx[0][r * SXP + lane + 192] = (x3 - mu) * rs * ln_g[lane + 192] + ln_b[lane + 192];
    }
    __syncthreads();

    const int kg  = tid >> 4;
    const int row = (tid >> 2) & 3;
    const int c4  = tid & 3;
    const int gc4 = cg * 4 + c4;
    const int kbase = kg * 16;

    #pragma unroll
    for (int m = 0; m < 3; ++m) {
        const float4* W4 = reinterpret_cast<const float4*>(m == 0 ? Wq : (m == 1 ? Wk : Wv));
        float4 a = {0, 0, 0, 0};
        #pragma unroll
        for (int kk = 0; kk < 16; ++kk) {
            const int kr = kbase + kk;
            const float x = sx[m][row * SXP + kr];
            const float4 w = W4[kr * 64 + gc4];
            a.x += x * w.x; a.y += x * w.y; a.z += x * w.z; a.w += x * w.w;
        }
        *reinterpret_cast<float4*>(&partF[(kg * 16 + row * 4 + c4) * 4]) = a;
        __syncthreads();
        if (tid < 64) {
            const int rr = tid >> 4, cc = tid & 15;
            float sum = 0.f;
            #pragma unroll
            for (int g = 0; g < 16; ++g) sum += partF[g * 64 + rr * 16 + cc];
            if      (m == 0) spq[rr][cc] = sum;
            else if (m == 1) spk[rr][cc] = sum;
            else             pv[(size_t)(rbase + rr) * D_ + cg * 16 + cc] = sum;
        }
        __syncthreads();
    }

    if (tid < 64) {
        const int rr = tid >> 4, cc = tid & 15;
        float d = spq[rr][cc] * spk[rr][cc];
        #pragma unroll
        for (int m = 8; m >= 1; m >>= 1) d += __shfl_xor(d, m, 64);
        if (cc == 0) qkpart[(size_t)(rbase + rr) * 16 + cg] = d;
    }
}

// K2: grid 256 = block per (b,i). All 8 heads: Phi/Psi, softmax (attn -> dout),
// mid (in LDS), then fc + bias + residual — no kernel boundary between them.
__global__ __launch_bounds__(256) void k_attn_fc(
    const float* __restrict__ q, const float* __restrict__ t, const float* __restrict__ omega,
    const float* __restrict__ s, const float* __restrict__ fc_w, const float* __restrict__ fc_b,
    const float* __restrict__ pv, const float* __restrict__ qkpart,
    float* __restrict__ dout)
{
    const int blk = blockIdx.x;
    const int b = blk >> 7;
    const int i = blk & (L_ - 1);
    const int tid = threadIdx.x;

    __shared__ __align__(16) float sQKp[L_ * 16];   // 8 KB staged half-head partials
    __shared__ __align__(16) float sQK[L_ * H_];    // combined [j][h] (4 KB)
    __shared__ __align__(16) float sOm[L_];
    __shared__ __align__(16) float sAttn[H_][L_];   // 4 KB
    __shared__ __align__(16) float sMid[D_];
    __shared__ float sPhi[L_], sPsi[L_], st[L_], sS[R_];

    {   // staging
        const float4* qkp4 = reinterpret_cast<const float4*>(qkpart + (size_t)b * L_ * 16);
        reinterpret_cast<float4*>(sQKp)[tid]       = qkp4[tid];
        reinterpret_cast<float4*>(sQKp)[tid + 256] = qkp4[tid + 256];
        if (tid < 32) {
            reinterpret_cast<float4*>(sOm)[tid] =
                reinterpret_cast<const float4*>(omega + ((size_t)(b * L_ + i)) * L_)[tid];
            reinterpret_cast<float4*>(st)[tid] =
                reinterpret_cast<const float4*>(t + (size_t)b * L_)[tid];
        }
        if (tid < R_) sS[tid] = s[tid];
    }
    __syncthreads();

    // combine half-head dots; Phi/Psi per j
    if (tid < 128) {
        #pragma unroll
        for (int h = 0; h < H_; ++h)
            sQK[tid * H_ + h] = sQKp[tid * 16 + 2 * h] + sQKp[tid * 16 + 2 * h + 1];
        const float dtv = fabsf(st[i] - st[tid]);
        float Phi = 0.f, Psi = 0.f;
        #pragma unroll
        for (int r = 0; r < R_; ++r) {
            const float e = expf(-dtv * sS[r]);
            Phi += e;
            Psi += e * e;
        }
        sPhi[tid] = Phi;
        sPsi[tid] = Psi;
    }
    __syncthreads();

    // softmax: wave w handles heads 2w, 2w+1; lanes cover j and j+64
    const int w = tid >> 6, lane = tid & 63;
    const float invtemp = 0.17677669529663687f;  // 1/sqrt(32)
    #pragma unroll
    for (int pass = 0; pass < 2; ++pass) {
        const int h = w * 2 + pass;
        const int j0 = lane, j1 = lane + 64;
        float l0 = (j0 <= i) ? sOm[j0] * sPsi[j0] * sQK[j0 * H_ + h] * invtemp : -3.0e38f;
        float l1 = (j1 <= i) ? sOm[j1] * sPsi[j1] * sQK[j1 * H_ + h] * invtemp : -3.0e38f;
        const float mx = wredmax64(fmaxf(l0, l1));
        const float e0 = (j0 <= i) ? expf(l0 - mx) : 0.f;
        const float e1 = (j1 <= i) ? expf(l1 - mx) : 0.f;
        const float inv = 1.0f / wredsum64(e0 + e1);
        const float a0 = e0 * inv, a1 = e1 * inv;
        sAttn[h][j0] = a0;
        sAttn[h][j1] = a1;
        const size_t ab = (size_t)BL_ * D_ + (((size_t)(b * H_ + h) * L_ + i) * L_);
        dout[ab + j0] = a0;
        dout[ab + j1] = a1;
    }
    __syncthreads();

    // mid[c] = sum_{j<=i} attn[h(c)][j] * Phi[j] * pv[b,j,c]  (coalesced over c)
    {
        const int h = tid >> 5;                  // head of col tid
        const float* pvb = pv + (size_t)b * L_ * D_ + tid;
        float acc = 0.f;
        #pragma unroll 4
        for (int j = 0; j <= i; ++j)
            acc += sAttn[h][j] * sPhi[j] * pvb[j * D_];
        sMid[tid] = acc;
    }
    __syncthreads();

    // fc + bias + residual (coalesced over c)
    {
        const size_t orow = (size_t)(b * L_ + i) * D_;
        float r = fc_b[tid] + q[orow + tid];
        const float* fwc = fc_w + tid;
        #pragma unroll 8
        for (int kk = 0; kk < D_; ++kk)
            r += sMid[kk] * fwc[kk * D_];
        dout[orow + tid] = r;
    }
}

extern "C" void kernel_launch(void* const* d_in, const int* in_sizes, int n_in,
                              void* d_out, int out_size, void* d_ws, size_t ws_size,
                              hipStream_t stream) {
    const float* q     = (const float*)d_in[0];
    const float* k     = (const float*)d_in[1];
    const float* v     = (const float*)d_in[2];
    const float* t     = (const float*)d_in[3];
    const float* omega = (const float*)d_in[4];
    // d_in[5] = mask (bool) — causal triu(1), hardcoded as j<=i, not read
    const float* Wq    = (const float*)d_in[6];
    const float* Wk    = (const float*)d_in[7];
    const float* Wv    = (const float*)d_in[8];
    const float* s     = (const float*)d_in[9];
    const float* fc_w  = (const float*)d_in[10];
    const float* fc_b  = (const float*)d_in[11];
    const float* ln_g  = (const float*)d_in[12];
    const float* ln_b  = (const float*)d_in[13];

    float* ws     = (float*)d_ws;
    float* pv     = ws;               // BL*D  = 65536 floats
    float* qkpart = ws + 65536;       // BL*16 = 4096 floats
    float* out    = (float*)d_out;    // [0,65536): out (B,L,D); [65536,327680): attn (B,H,L,L)

    hipLaunchKernelGGL(k_proj, dim3(1024), dim3(256), 0, stream,
                       q, k, v, Wq, Wk, Wv, ln_g, ln_b, pv, qkpart);
    hipLaunchKernelGGL(k_attn_fc, dim3(256), dim3(256), 0, stream,
                       q, t, omega, s, fc_w, fc_b, pv, qkpart, out);
}